// Round 13
// baseline (109.179 us; speedup 1.0000x reference)
//
#include <hip/hip_runtime.h>

#define NB 8
#define C 256
#define HW 52
#define P (HW*HW)            // 2704
#define NTOPK 4
#define SCALE 0.0625f

typedef float nt_f32x4 __attribute__((ext_vector_type(4)));

// exact unsigned div helpers (verified ranges)
static __device__ __forceinline__ int d7(int v)  { return (v*9363) >> 16; }   // v <= 3135
static __device__ __forceinline__ int d56(int v) { return (v*18725) >> 20; }  // v <= 3135
static __device__ __forceinline__ int d13(int v) { return (v*10083) >> 17; }  // v <= 675

// scratch layout (floats) at front of d_out
#define OFF_YR  0               // 8*256*64   = 131072   [b][c][reg]
#define OFF_XGT 131072          // 8*256*256  = 524288   [b][pos][c]
#define OFF_XRT 655360          // 8*64*256   = 131072   [b][reg][c]
#define OFF_M   786432          // 65536
#define OFF_U   851968          // 256
#define OFF_V2  852224          // 256
#define OFF_C0  852480          // 16
#define OFF_YT  852496          // 8*2704*256 = 5537792  [b][pos][c] (ends ~25.6 MB)

// ============ Ka: blocks 0..1023 pool (yr / xgT,xrT); 1024..1088 prep;
//              1089..2464 y NCHW->N(HW)C transpose into yT ==================
__global__ __launch_bounds__(256) void ka_pool_prep_tr(
    const float* __restrict__ x, const float* __restrict__ y,
    const float* __restrict__ qw, const float* __restrict__ qb,
    const float* __restrict__ kw, const float* __restrict__ kb,
    float* __restrict__ scr)
{
    __shared__ float sm[4*P];           // 43.3 KB
    __shared__ float gbuf[4][256];
    __shared__ float pbuf[4][64];
    const int tid = threadIdx.x;
    const int bx = blockIdx.x;

    float* yr  = scr + OFF_YR;
    float* xgT = scr + OFF_XGT;
    float* xrT = scr + OFF_XRT;
    float* M   = scr + OFF_M;
    float* u   = scr + OFF_U;
    float* v2  = scr + OFF_V2;
    float* c0p = scr + OFF_C0;
    float* yT  = scr + OFF_YT;

    if (bx >= 1089) {                   // ---- transpose path: 64c x 64pos tile ----
        const int tb = bx - 1089;
        const int b = tb / 172;
        const int rem = tb - b*172;
        const int ct = rem / 43;
        const int pt = rem - ct*43;
        const int c0 = ct*64, pos0 = pt*64;
        float* tile = sm;               // [64][65]
        const float* ysrc = y + ((size_t)(b*256 + c0))*P;
        #pragma unroll
        for (int p = 0; p < 4; p++) {
            const int cr = p*16 + (tid>>4);
            const int f4 = tid&15;
            const int pos = pos0 + f4*4;
            if (pos < P) {
                const float4 v = *(const float4*)(ysrc + (size_t)cr*P + pos);
                float* d = tile + cr*65 + f4*4;
                d[0]=v.x; d[1]=v.y; d[2]=v.z; d[3]=v.w;
            }
        }
        __syncthreads();
        #pragma unroll
        for (int p = 0; p < 4; p++) {
            const int pj = p*16 + (tid>>4);
            const int c4 = tid&15;
            const int pos = pos0 + pj;
            if (pos < P) {
                float4 v;
                v.x = tile[(c4*4+0)*65 + pj];
                v.y = tile[(c4*4+1)*65 + pj];
                v.z = tile[(c4*4+2)*65 + pj];
                v.w = tile[(c4*4+3)*65 + pj];
                *(float4*)(yT + ((size_t)(b*P + pos))*256 + c0 + c4*4) = v;
            }
        }
        return;
    }

    if (bx >= 1024) {                   // ---- prep path ----
        const int pb = bx - 1024;
        if (pb == 64) {
            float ua = 0.f, va = 0.f;
            for (int e = 0; e < 256; e++) {
                ua += qb[e] * kw[e*256 + tid];
                va += kb[e] * qw[e*256 + tid];
            }
            u[tid] = ua; v2[tid] = va;
            if (tid == 0) {
                float c = 0.f;
                for (int e = 0; e < 256; e++) c += qb[e]*kb[e];
                c0p[0] = c;
            }
            return;
        }
        const int cx0 = pb * 4;
        float (*wqs)[4] = (float(*)[4])sm;
        *(float4*)&wqs[tid][0] = *(const float4*)(qw + tid*256 + cx0);
        __syncthreads();
        float a0=0.f, a1=0.f, a2=0.f, a3=0.f;
        #pragma unroll 4
        for (int o = 0; o < 256; o++) {
            const float wk = kw[o*256 + tid];
            const float4 wq = *(const float4*)&wqs[o][0];
            a0 += wq.x*wk; a1 += wq.y*wk; a2 += wq.z*wk; a3 += wq.w*wk;
        }
        M[(cx0+0)*256 + tid] = a0;
        M[(cx0+1)*256 + tid] = a1;
        M[(cx0+2)*256 + tid] = a2;
        M[(cx0+3)*256 + tid] = a3;
        return;
    }

    // ---- pool path: wave w handles plane bx*4+w (proj/b uniform per block) --
    const int w = tid >> 6, lane = tid & 63;
    const int pl = bx*4 + w;
    const int proj = pl >> 11;
    const int bcid = pl & 2047;                     // b*256 + c
    const float* src = (proj ? y : x) + (size_t)bcid * P;
    float* plane = sm + w*P;
    {   // vectorized plane load: 676 float4
        const float4* s4 = (const float4*)src;
        float4* p4 = (float4*)plane;
        for (int g = lane; g < 676; g += 64) p4[g] = s4[g];
    }
    __syncthreads();
    const int jh = lane >> 3, jw = lane & 7;
    const int y0 = jh*7, x0 = jw*7;
    const int ry = min(7, HW - y0), rx = min(7, HW - x0);
    float s = 0.f;
    for (int dy = 0; dy < ry; ++dy) {
        const float* row = plane + (y0 + dy)*HW + x0;
        for (int dx = 0; dx < rx; ++dx) s += row[dx];
    }
    const float pooled = s / (float)(ry*rx);
    if (proj) {
        yr[bcid*64 + lane] = pooled;                // [b][c][reg], coalesced
    } else {
        // exchange via LDS, then write 4-channel float4 rows of xgT/xrT
        pbuf[w][lane] = pooled;
        const float* r0 = plane + y0*HW + x0;
        gbuf[w][lane*4+0] = r0[0];
        gbuf[w][lane*4+1] = r0[1];
        gbuf[w][lane*4+2] = r0[2];
        gbuf[w][lane*4+3] = (x0 + 3 < HW) ? r0[3] : 0.f;
        __syncthreads();
        const int pl0 = bx*4;
        const int b  = (pl0 & 2047) >> 8;
        const int c0 = pl0 & 255;                   // multiple of 4
        {   // xgT[b][pos][c0..c0+3]
            const int pos = tid;
            float4 v;
            v.x = gbuf[0][pos]; v.y = gbuf[1][pos];
            v.z = gbuf[2][pos]; v.w = gbuf[3][pos];
            *(float4*)(xgT + ((size_t)(b*256 + pos))*256 + c0) = v;
        }
        if (tid < 64) {                             // xrT[b][reg][c0..c0+3]
            float4 v;
            v.x = pbuf[0][tid]; v.y = pbuf[1][tid];
            v.z = pbuf[2][tid]; v.w = pbuf[3][tid];
            *(float4*)(xrT + ((size_t)(b*64 + tid))*256 + c0) = v;
        }
    }
}

// ============ Kb: per (b,r): in-block wave-matvec (G rows + Gr, LDS-staged xs)
//              + a_r row + top-4 + vals (direct yT reads; small LDS) =========
__global__ __launch_bounds__(256) void kb_topk_vals(
    const float* __restrict__ scr,
    float* __restrict__ arT, int* __restrict__ idxout, float* __restrict__ vals)
{
    const int b = blockIdx.y, r = blockIdx.x;
    const int tid = threadIdx.x, w = tid >> 6, lane = tid & 63;

    const float* yr  = scr + OFF_YR;
    const float* xgT = scr + OFF_XGT;
    const float* xrT = scr + OFF_XRT;
    const float* M   = scr + OFF_M;
    const float* uu  = scr + OFF_U;
    const float* v2  = scr + OFF_V2;
    const float* c0p = scr + OFF_C0;
    const float* yT  = scr + OFF_YT;

    __shared__ float xs[5][256];    // 4 xgT rows + 1 xrT row   (5 KB)
    __shared__ float Gs[4][260];    // padded: breaks 4-way t-stride aliasing (4.1 KB)
    __shared__ float Grs[256];      // 1 KB
    __shared__ float pdot[4][64];   // 1 KB
    __shared__ float aux[12];       // [0..3]=H[t], [4..7]=ci partials
    __shared__ int gsh;

    // Phase A0: stage the 5 input rows (coalesced)
    #pragma unroll
    for (int j = 0; j < 4; j++)
        xs[j][tid] = xgT[((size_t)(b*256 + r*4 + j))*256 + tid];
    xs[4][tid] = xrT[((size_t)(b*64 + r))*256 + tid];
    __syncthreads();

    // Phase A1: wave-matvec — thread owns column o = tid; no barriers in loop.
    {
        float a0=0.f, a1=0.f, a2=0.f, a3=0.f, a4=0.f;
        #pragma unroll 8
        for (int c = 0; c < 256; c++) {
            const float m = M[c*256 + tid];     // coalesced 1KB/wave
            a0 += xs[0][c]*m; a1 += xs[1][c]*m;
            a2 += xs[2][c]*m; a3 += xs[3][c]*m;
            a4 += xs[4][c]*m;
        }
        const float uo = uu[tid];
        Gs[0][tid] = a0 + uo;
        Gs[1][tid] = a1 + uo;
        Gs[2][tid] = a2 + uo;
        Gs[3][tid] = a3 + uo;
        Grs[tid]   = a4 + uo;
    }
    // H[t] (warp w -> t=w) and ci partials from xs (LDS, conflict-free)
    {
        float hacc = 0.f;
        #pragma unroll
        for (int j = 0; j < 4; j++) {
            const int c = lane + j*64;
            hacc += xs[w][c] * v2[c];
        }
        #pragma unroll
        for (int off = 32; off >= 1; off >>= 1) hacc += __shfl_xor(hacc, off);
        if (lane == 0) aux[w] = hacc + c0p[0];

        const int c = w*64 + lane;
        float cacc = xs[4][c] * v2[c];
        #pragma unroll
        for (int off = 32; off >= 1; off >>= 1) cacc += __shfl_xor(cacc, off);
        if (lane == 0) aux[4 + w] = cacc;
    }
    __syncthreads();

    // a_r row: warp w covers c-chunk w (yr reads coalesced per iter)
    {
        const float* yrB = yr + b*C*64;
        float d = 0.f;
        #pragma unroll 8
        for (int cc = 0; cc < 64; cc++) {
            const int c = w*64 + cc;
            d += Grs[c] * yrB[c*64 + lane];
        }
        pdot[w][lane] = d;
    }
    __syncthreads();

    // warp 0: full dot, arT write, top-4 (low-index tie-break)
    if (w == 0) {
        const float ci = aux[4] + aux[5] + aux[6] + aux[7] + c0p[0];
        const float dot = pdot[0][lane] + pdot[1][lane] + pdot[2][lane]
                        + pdot[3][lane] + ci;
        arT[(b*64 + lane)*64 + r] = dot * SCALE;
        float v = dot;
        const int my = lane;
        #pragma unroll
        for (int t = 0; t < NTOPK; t++) {
            float bv = v; int bi = my;
            #pragma unroll
            for (int off = 32; off >= 1; off >>= 1) {
                const float ov = __shfl_xor(bv, off);
                const int   oi = __shfl_xor(bi, off);
                if (ov > bv || (ov == bv && oi < bi)) { bv = ov; bi = oi; }
            }
            if (lane == 0) {
                idxout[(b*64 + r)*NTOPK + t] = bi;
                if (t == NTOPK-1) gsh = bi;
            }
            if (my == bi) v = -3.0e38f;
        }
    }
    __syncthreads();

    // vals[b,r,t,k2] = SCALE*(G_row . yT_row + H) — direct yT reads (L2/L3-hot)
    const int g = gsh;
    const int gy = g >> 3, gx = g & 7;
    if (tid < NTOPK*49) {
        const int t = tid / 49, k2 = tid - (tid/49)*49;
        const int qX = (r & 7)*7 + t;
        const int dy = d7(k2), dx = k2 - dy*7;
        const int kY = gy*7 + dy, kX = gx*7 + dx;
        float res = 0.f;
        if (qX < HW && kY < HW && kX < HW) {
            const float4* Gp = (const float4*)&Gs[t][0];
            const float4* Yp = (const float4*)(yT + ((size_t)(b*P + kY*HW + kX))*256);
            float dot = 0.f;
            #pragma unroll 8
            for (int cc = 0; cc < 64; cc++) {
                const float4 a = Gp[cc], yy = Yp[cc];
                dot += a.x*yy.x + a.y*yy.y + a.z*yy.z + a.w*yy.w;
            }
            res = SCALE * (dot + aux[t]);
        }
        vals[((b*64 + r)*NTOPK + t)*49 + k2] = res;
    }
}

// ============ Kc: final fill — one block per (b, Y1, X1), nontemporal stores =
__global__ __launch_bounds__(256) void kc_fill(
    const float* __restrict__ arT, const float* __restrict__ vals,
    const int* __restrict__ idx, float* __restrict__ out)
{
    const int b = blockIdx.y;
    const int yx = blockIdx.x;            // Y1*52 + X1
    const int Y1 = yx / HW, X1 = yx % HW;
    const int r1 = (Y1/7)*8 + X1/7;
    const int q1 = (Y1%7)*7 + X1%7;
    const int p2 = r1*49 + q1;
    const int yy = p2/56, xx = p2 - 56*yy;
    const int regB = (yy/7)*8 + xx/7;

    __shared__ float acol[64];
    __shared__ float vrow[49];
    const int tid = threadIdx.x;
    if (tid < 64) acol[tid] = arT[(b*64 + regB)*64 + tid];
    int ovr = -1;
    if (q1 < NTOPK) {
        ovr = idx[(b*64 + r1)*NTOPK + q1];
        if (tid < 49) vrow[tid] = vals[((b*64 + r1)*NTOPK + q1)*49 + tid];
    }
    __syncthreads();

    float* plane = out + (size_t)(b*P + yx) * P;
    for (int u = tid; u < 676; u += 256) {       // 676 = 52*13 float4 groups
        const int Y2 = d13(u);
        const int g4 = u - Y2*13;
        const int X2b = g4*4;
        const int ry2 = d7(Y2);
        const int my2 = Y2 - ry2*7;
        float res[4];
        #pragma unroll
        for (int j = 0; j < 4; j++) {
            const int X2 = X2b + j;
            const int rx2 = d7(X2);
            const int mx2 = X2 - rx2*7;
            const int r2 = ry2*8 + rx2;
            const int k2 = my2*7 + mx2;
            const int P1 = r2*49 + k2;
            const int Yp = d56(P1);
            const int Xp = P1 - Yp*56;
            const int regA = d7(Yp)*8 + d7(Xp);
            float v = acol[regA];
            if (r2 == ovr) v = vrow[k2];
            res[j] = v;
        }
        nt_f32x4 o;
        o.x = res[0]; o.y = res[1]; o.z = res[2]; o.w = res[3];
        __builtin_nontemporal_store(o, (nt_f32x4*)(plane + Y2*HW + X2b));
    }
}

extern "C" void kernel_launch(void* const* d_in, const int* in_sizes, int n_in,
                              void* d_out, int out_size, void* d_ws, size_t ws_size,
                              hipStream_t stream)
{
    const float* x  = (const float*)d_in[0];
    const float* y  = (const float*)d_in[1];
    const float* qw = (const float*)d_in[2];
    const float* qb = (const float*)d_in[3];
    const float* kw = (const float*)d_in[4];
    const float* kb = (const float*)d_in[5];
    float* out = (float*)d_out;

    // Large scratch at front of d_out (~25.6 MB << 234 MB out buffer);
    // fully consumed by kb before kc_fill overwrites d_out.
    float* scr = out;

    // fill-consumed small arrays stay in d_ws
    float* ws  = (float*)d_ws;
    float* arT = ws;                          // 8*64*64 = 32768
    float* vls = arT + 32768;                 // 8*64*4*49 = 100352
    int*   idx = (int*)(vls + 100352);        // 8*64*4 ints

    ka_pool_prep_tr<<<2465, 256, 0, stream>>>(x, y, qw, qb, kw, kb, scr);
    kb_topk_vals<<<dim3(64, 8), 256, 0, stream>>>(scr, arT, idx, vls);
    kc_fill<<<dim3(P, 8), 256, 0, stream>>>(arT, vls, idx, out);
}

// Round 14
// 103.225 us; speedup vs baseline: 1.0577x; 1.0577x over previous
//
#include <hip/hip_runtime.h>

#define NB 8
#define C 256
#define HW 52
#define P (HW*HW)            // 2704
#define NTOPK 4
#define SCALE 0.0625f

typedef float nt_f32x4 __attribute__((ext_vector_type(4)));

// exact unsigned div helpers (verified ranges)
static __device__ __forceinline__ int d7(int v)  { return (v*9363) >> 16; }   // v <= 3135
static __device__ __forceinline__ int d56(int v) { return (v*18725) >> 20; }  // v <= 3135
static __device__ __forceinline__ int d13(int v) { return (v*10083) >> 17; }  // v <= 675

// scratch layout (floats) at front of d_out
#define OFF_YR  0               // 8*256*64   = 131072   [b][c][reg]
#define OFF_XGT 131072          // 8*256*256  = 524288   [b][pos][c]
#define OFF_XRT 655360          // 8*64*256   = 131072   [b][reg][c]
#define OFF_M   786432          // 65536
#define OFF_U   851968          // 256
#define OFF_V2  852224          // 256
#define OFF_C0  852480          // 16
#define OFF_YT  852496          // 8*2704*256 = 5537792  [b][pos][c] (ends ~25.6 MB)

// ============ Ka: blocks 0..1023 pool (yr / xgT,xrT); 1024..1088 prep;
//              1089..2464 y NCHW->N(HW)C transpose into yT ==================
__global__ __launch_bounds__(256) void ka_pool_prep_tr(
    const float* __restrict__ x, const float* __restrict__ y,
    const float* __restrict__ qw, const float* __restrict__ qb,
    const float* __restrict__ kw, const float* __restrict__ kb,
    float* __restrict__ scr)
{
    __shared__ float sm[4*P];           // 43.3 KB
    __shared__ float gbuf[4][256];
    __shared__ float pbuf[4][64];
    const int tid = threadIdx.x;
    const int bx = blockIdx.x;

    float* yr  = scr + OFF_YR;
    float* xgT = scr + OFF_XGT;
    float* xrT = scr + OFF_XRT;
    float* M   = scr + OFF_M;
    float* u   = scr + OFF_U;
    float* v2  = scr + OFF_V2;
    float* c0p = scr + OFF_C0;
    float* yT  = scr + OFF_YT;

    if (bx >= 1089) {                   // ---- transpose path: 64c x 64pos tile ----
        const int tb = bx - 1089;
        const int b = tb / 172;
        const int rem = tb - b*172;
        const int ct = rem / 43;
        const int pt = rem - ct*43;
        const int c0 = ct*64, pos0 = pt*64;
        float* tile = sm;               // [64][65]
        const float* ysrc = y + ((size_t)(b*256 + c0))*P;
        #pragma unroll
        for (int p = 0; p < 4; p++) {
            const int cr = p*16 + (tid>>4);
            const int f4 = tid&15;
            const int pos = pos0 + f4*4;
            if (pos < P) {
                const float4 v = *(const float4*)(ysrc + (size_t)cr*P + pos);
                float* d = tile + cr*65 + f4*4;
                d[0]=v.x; d[1]=v.y; d[2]=v.z; d[3]=v.w;
            }
        }
        __syncthreads();
        #pragma unroll
        for (int p = 0; p < 4; p++) {
            const int pj = p*16 + (tid>>4);
            const int c4 = tid&15;
            const int pos = pos0 + pj;
            if (pos < P) {
                float4 v;
                v.x = tile[(c4*4+0)*65 + pj];
                v.y = tile[(c4*4+1)*65 + pj];
                v.z = tile[(c4*4+2)*65 + pj];
                v.w = tile[(c4*4+3)*65 + pj];
                *(float4*)(yT + ((size_t)(b*P + pos))*256 + c0 + c4*4) = v;
            }
        }
        return;
    }

    if (bx >= 1024) {                   // ---- prep path ----
        const int pb = bx - 1024;
        if (pb == 64) {
            float ua = 0.f, va = 0.f;
            for (int e = 0; e < 256; e++) {
                ua += qb[e] * kw[e*256 + tid];
                va += kb[e] * qw[e*256 + tid];
            }
            u[tid] = ua; v2[tid] = va;
            if (tid == 0) {
                float c = 0.f;
                for (int e = 0; e < 256; e++) c += qb[e]*kb[e];
                c0p[0] = c;
            }
            return;
        }
        const int cx0 = pb * 4;
        float (*wqs)[4] = (float(*)[4])sm;
        *(float4*)&wqs[tid][0] = *(const float4*)(qw + tid*256 + cx0);
        __syncthreads();
        float a0=0.f, a1=0.f, a2=0.f, a3=0.f;
        #pragma unroll 4
        for (int o = 0; o < 256; o++) {
            const float wk = kw[o*256 + tid];
            const float4 wq = *(const float4*)&wqs[o][0];
            a0 += wq.x*wk; a1 += wq.y*wk; a2 += wq.z*wk; a3 += wq.w*wk;
        }
        M[(cx0+0)*256 + tid] = a0;
        M[(cx0+1)*256 + tid] = a1;
        M[(cx0+2)*256 + tid] = a2;
        M[(cx0+3)*256 + tid] = a3;
        return;
    }

    // ---- pool path: wave w handles plane bx*4+w (proj/b uniform per block) --
    const int w = tid >> 6, lane = tid & 63;
    const int pl = bx*4 + w;
    const int proj = pl >> 11;
    const int bcid = pl & 2047;                     // b*256 + c
    const float* src = (proj ? y : x) + (size_t)bcid * P;
    float* plane = sm + w*P;
    {   // vectorized plane load: 676 float4
        const float4* s4 = (const float4*)src;
        float4* p4 = (float4*)plane;
        for (int g = lane; g < 676; g += 64) p4[g] = s4[g];
    }
    __syncthreads();
    const int jh = lane >> 3, jw = lane & 7;
    const int y0 = jh*7, x0 = jw*7;
    const int ry = min(7, HW - y0), rx = min(7, HW - x0);
    float s = 0.f;
    for (int dy = 0; dy < ry; ++dy) {
        const float* row = plane + (y0 + dy)*HW + x0;
        for (int dx = 0; dx < rx; ++dx) s += row[dx];
    }
    const float pooled = s / (float)(ry*rx);
    if (proj) {
        yr[bcid*64 + lane] = pooled;                // [b][c][reg], coalesced
    } else {
        // exchange via LDS, then write 4-channel float4 rows of xgT/xrT
        pbuf[w][lane] = pooled;
        const float* r0 = plane + y0*HW + x0;
        gbuf[w][lane*4+0] = r0[0];
        gbuf[w][lane*4+1] = r0[1];
        gbuf[w][lane*4+2] = r0[2];
        gbuf[w][lane*4+3] = (x0 + 3 < HW) ? r0[3] : 0.f;
        __syncthreads();
        const int pl0 = bx*4;
        const int b  = (pl0 & 2047) >> 8;
        const int c0 = pl0 & 255;                   // multiple of 4
        {   // xgT[b][pos][c0..c0+3]
            const int pos = tid;
            float4 v;
            v.x = gbuf[0][pos]; v.y = gbuf[1][pos];
            v.z = gbuf[2][pos]; v.w = gbuf[3][pos];
            *(float4*)(xgT + ((size_t)(b*256 + pos))*256 + c0) = v;
        }
        if (tid < 64) {                             // xrT[b][reg][c0..c0+3]
            float4 v;
            v.x = pbuf[0][tid]; v.y = pbuf[1][tid];
            v.z = pbuf[2][tid]; v.w = pbuf[3][tid];
            *(float4*)(xrT + ((size_t)(b*64 + tid))*256 + c0) = v;
        }
    }
}

// ============ Kb: per (b,r): in-block wave-matvec (G rows + Gr, LDS-staged xs)
//              + a_r row + top-4 + vals (yT staged) ==========================
__global__ __launch_bounds__(256) void kb_topk_vals(
    const float* __restrict__ scr,
    float* __restrict__ arT, int* __restrict__ idxout, float* __restrict__ vals)
{
    const int b = blockIdx.y, r = blockIdx.x;
    const int tid = threadIdx.x, w = tid >> 6, lane = tid & 63;

    const float* yr  = scr + OFF_YR;
    const float* xgT = scr + OFF_XGT;
    const float* xrT = scr + OFF_XRT;
    const float* M   = scr + OFF_M;
    const float* uu  = scr + OFF_U;
    const float* v2  = scr + OFF_V2;
    const float* c0p = scr + OFF_C0;
    const float* yT  = scr + OFF_YT;

    __shared__ float xs[5][256];    // 4 xgT rows + 1 xrT row
    __shared__ float Gs[4][256];
    __shared__ float Grs[256];
    __shared__ float pdot[4][64];
    __shared__ float aux[12];       // [0..3]=H[t], [4..7]=ci partials
    __shared__ int gsh;
    __shared__ float Ys[49][260];

    // Phase A0: stage the 5 input rows (coalesced)
    #pragma unroll
    for (int j = 0; j < 4; j++)
        xs[j][tid] = xgT[((size_t)(b*256 + r*4 + j))*256 + tid];
    xs[4][tid] = xrT[((size_t)(b*64 + r))*256 + tid];
    __syncthreads();

    // Phase A1: wave-matvec — thread owns column o = tid; no barriers in loop.
    {
        float a0=0.f, a1=0.f, a2=0.f, a3=0.f, a4=0.f;
        #pragma unroll 8
        for (int c = 0; c < 256; c++) {
            const float m = M[c*256 + tid];     // coalesced 1KB/wave
            a0 += xs[0][c]*m; a1 += xs[1][c]*m;
            a2 += xs[2][c]*m; a3 += xs[3][c]*m;
            a4 += xs[4][c]*m;
        }
        const float uo = uu[tid];
        Gs[0][tid] = a0 + uo;
        Gs[1][tid] = a1 + uo;
        Gs[2][tid] = a2 + uo;
        Gs[3][tid] = a3 + uo;
        Grs[tid]   = a4 + uo;
    }
    // H[t] (warp w -> t=w) and ci partials from xs (LDS, conflict-free)
    {
        float hacc = 0.f;
        #pragma unroll
        for (int j = 0; j < 4; j++) {
            const int c = lane + j*64;
            hacc += xs[w][c] * v2[c];
        }
        #pragma unroll
        for (int off = 32; off >= 1; off >>= 1) hacc += __shfl_xor(hacc, off);
        if (lane == 0) aux[w] = hacc + c0p[0];

        const int c = w*64 + lane;
        float cacc = xs[4][c] * v2[c];
        #pragma unroll
        for (int off = 32; off >= 1; off >>= 1) cacc += __shfl_xor(cacc, off);
        if (lane == 0) aux[4 + w] = cacc;
    }
    __syncthreads();

    // a_r row: warp w covers c-chunk w (yr reads coalesced per iter)
    {
        const float* yrB = yr + b*C*64;
        float d = 0.f;
        #pragma unroll 8
        for (int cc = 0; cc < 64; cc++) {
            const int c = w*64 + cc;
            d += Grs[c] * yrB[c*64 + lane];
        }
        pdot[w][lane] = d;
    }
    __syncthreads();

    // warp 0: full dot, arT write, top-4 (low-index tie-break)
    if (w == 0) {
        const float ci = aux[4] + aux[5] + aux[6] + aux[7] + c0p[0];
        const float dot = pdot[0][lane] + pdot[1][lane] + pdot[2][lane]
                        + pdot[3][lane] + ci;
        arT[(b*64 + lane)*64 + r] = dot * SCALE;
        float v = dot;
        const int my = lane;
        #pragma unroll
        for (int t = 0; t < NTOPK; t++) {
            float bv = v; int bi = my;
            #pragma unroll
            for (int off = 32; off >= 1; off >>= 1) {
                const float ov = __shfl_xor(bv, off);
                const int   oi = __shfl_xor(bi, off);
                if (ov > bv || (ov == bv && oi < bi)) { bv = ov; bi = oi; }
            }
            if (lane == 0) {
                idxout[(b*64 + r)*NTOPK + t] = bi;
                if (t == NTOPK-1) gsh = bi;
            }
            if (my == bi) v = -3.0e38f;
        }
    }
    __syncthreads();

    // stage yT rows for region g into LDS [k2][c] — coalesced float4
    const int g = gsh;
    const int gy = g >> 3, gx = g & 7;
    for (int i = tid; i < 49*64; i += 256) {
        const int k2 = i >> 6, f4 = i & 63;
        const int dy = d7(k2), dx = k2 - dy*7;
        const int kY = gy*7 + dy, kX = gx*7 + dx;
        float4 v = make_float4(0.f, 0.f, 0.f, 0.f);
        if (kY < HW && kX < HW)
            v = *(const float4*)(yT + ((size_t)(b*P + kY*HW + kX))*256 + f4*4);
        *(float4*)&Ys[k2][f4*4] = v;
    }
    __syncthreads();

    // vals[b,r,t,k2] = SCALE*(G_row . y_col + H)
    if (tid < NTOPK*49) {
        const int t = tid / 49, k2 = tid - (tid/49)*49;
        const int qX = (r & 7)*7 + t;
        const int dy = d7(k2), dx = k2 - dy*7;
        const int kY = gy*7 + dy, kX = gx*7 + dx;
        float res = 0.f;
        if (qX < HW && kY < HW && kX < HW) {
            const float4* Gp = (const float4*)&Gs[t][0];
            const float4* Yp = (const float4*)&Ys[k2][0];
            float dot = 0.f;
            #pragma unroll 8
            for (int cc = 0; cc < 64; cc++) {
                const float4 a = Gp[cc], yy = Yp[cc];
                dot += a.x*yy.x + a.y*yy.y + a.z*yy.z + a.w*yy.w;
            }
            res = SCALE * (dot + aux[t]);
        }
        vals[((b*64 + r)*NTOPK + t)*49 + k2] = res;
    }
}

// ============ Kc: final fill — one block per (b, Y1, X1), nontemporal stores =
__global__ __launch_bounds__(256) void kc_fill(
    const float* __restrict__ arT, const float* __restrict__ vals,
    const int* __restrict__ idx, float* __restrict__ out)
{
    const int b = blockIdx.y;
    const int yx = blockIdx.x;            // Y1*52 + X1
    const int Y1 = yx / HW, X1 = yx % HW;
    const int r1 = (Y1/7)*8 + X1/7;
    const int q1 = (Y1%7)*7 + X1%7;
    const int p2 = r1*49 + q1;
    const int yy = p2/56, xx = p2 - 56*yy;
    const int regB = (yy/7)*8 + xx/7;

    __shared__ float acol[64];
    __shared__ float vrow[49];
    const int tid = threadIdx.x;
    if (tid < 64) acol[tid] = arT[(b*64 + regB)*64 + tid];
    int ovr = -1;
    if (q1 < NTOPK) {
        ovr = idx[(b*64 + r1)*NTOPK + q1];
        if (tid < 49) vrow[tid] = vals[((b*64 + r1)*NTOPK + q1)*49 + tid];
    }
    __syncthreads();

    float* plane = out + (size_t)(b*P + yx) * P;
    for (int u = tid; u < 676; u += 256) {       // 676 = 52*13 float4 groups
        const int Y2 = d13(u);
        const int g4 = u - Y2*13;
        const int X2b = g4*4;
        const int ry2 = d7(Y2);
        const int my2 = Y2 - ry2*7;
        float res[4];
        #pragma unroll
        for (int j = 0; j < 4; j++) {
            const int X2 = X2b + j;
            const int rx2 = d7(X2);
            const int mx2 = X2 - rx2*7;
            const int r2 = ry2*8 + rx2;
            const int k2 = my2*7 + mx2;
            const int P1 = r2*49 + k2;
            const int Yp = d56(P1);
            const int Xp = P1 - Yp*56;
            const int regA = d7(Yp)*8 + d7(Xp);
            float v = acol[regA];
            if (r2 == ovr) v = vrow[k2];
            res[j] = v;
        }
        nt_f32x4 o;
        o.x = res[0]; o.y = res[1]; o.z = res[2]; o.w = res[3];
        __builtin_nontemporal_store(o, (nt_f32x4*)(plane + Y2*HW + X2b));
    }
}

extern "C" void kernel_launch(void* const* d_in, const int* in_sizes, int n_in,
                              void* d_out, int out_size, void* d_ws, size_t ws_size,
                              hipStream_t stream)
{
    const float* x  = (const float*)d_in[0];
    const float* y  = (const float*)d_in[1];
    const float* qw = (const float*)d_in[2];
    const float* qb = (const float*)d_in[3];
    const float* kw = (const float*)d_in[4];
    const float* kb = (const float*)d_in[5];
    float* out = (float*)d_out;

    // Large scratch at front of d_out (~25.6 MB << 234 MB out buffer);
    // fully consumed by kb before kc_fill overwrites d_out.
    float* scr = out;

    // fill-consumed small arrays stay in d_ws
    float* ws  = (float*)d_ws;
    float* arT = ws;                          // 8*64*64 = 32768
    float* vls = arT + 32768;                 // 8*64*4*49 = 100352
    int*   idx = (int*)(vls + 100352);        // 8*64*4 ints

    ka_pool_prep_tr<<<2465, 256, 0, stream>>>(x, y, qw, qb, kw, kb, scr);
    kb_topk_vals<<<dim3(64, 8), 256, 0, stream>>>(scr, arT, idx, vls);
    kc_fill<<<dim3(P, 8), 256, 0, stream>>>(arT, vls, idx, out);
}